// Round 10
// baseline (606.299 us; speedup 1.0000x reference)
//
#include <hip/hip_runtime.h>

// ---------------- problem constants ----------------
#define NVEC  131072      // 32*4096 vectors
#define DIM   64
#define K     512
#define DECAYF 0.99f
#define OMDF   0.01f
#define EPSF   1e-5f
#define NBLK_ASSIGN (NVEC / 64)   // 2048 blocks, 64 vectors each

// ---------------- output layout (floats, concatenated in return order) ----
#define Q_OFF    0
#define DIFF_OFF 8388608
#define IND_OFF  8388609
#define NE_OFF   8519681
#define NCS_OFF  8552449
#define NEA_OFF  8552961

// ---------------- ws layout (floats) — 332,800 floats = 1.331 MB ----
// (r4 passed with 1.340 MB, so ws_size >= that)
#define ET_OFF     0        // E^T : K x DIM
#define C_OFF      32768    // np-order sum(E*E, axis=0) : K
#define EPK_OFF    33280    // paired codes: [jp][d][2] : K x DIM
#define CSZ_OFF    66048    // csz per code : K (written by vq_nf)
#define DPART_OFF  66560    // per-assign-block diff partials : 2048
#define INDI_OFF   68608    // int indices : NVEC
#define PCNT_OFF   199680   // count partials : 4 x K
#define PESUMT_OFF 201728   // esum partials TRANSPOSED : [4][DIM][K]

// ============ prep: E^T, np-order C_j, and paired-code layout ============
__global__ __launch_bounds__(256) void vq_prep(const float* __restrict__ embed,
                                               float* __restrict__ ws) {
    #pragma clang fp contract(off)
    int j = blockIdx.x * 256 + threadIdx.x;   // 0..511
    float c = 0.0f;
    for (int d = 0; d < DIM; ++d) {
        float v = embed[d * K + j];           // coalesced across j
        ws[ET_OFF + j * DIM + d] = v;
        ws[EPK_OFF + (j >> 1) * (2 * DIM) + d * 2 + (j & 1)] = v;
        float t = v * v;
        c = c + t;
    }
    ws[C_OFF + j] = c;
}

// ============ main: d-split + j-paired np-replica argmin =================
// Wave = 32 vectors x 2 d-halves (f[32]/thread: no 64-reg residency fight).
// The np sequential fma chain is split mid-sequence: h=0 computes d=0..31,
// hands the partial to h=1 via shfl_xor(32), h=1 continues d=32..63 —
// EXACT same rounding sequence as the verified r2 kernel, one j-pair
// pipelined. Lanes process 2 codes at once (m.x/m.y share f[dd]) so the
// compiler can emit v_pk_fma_f32 (2x fp32 rate). K-split 2 across wave
// pairs; combine is lexicographic min == numpy first-min.
__global__ __launch_bounds__(256)
__attribute__((amdgpu_waves_per_eu(4, 4)))
void vq_assign(
    const float* __restrict__ x,
    const float* __restrict__ ET,      // ws + ET_OFF
    const float2* __restrict__ EPK,    // ws + EPK_OFF
    const float* __restrict__ Cn,      // ws + C_OFF
    int*   __restrict__ indI,          // ws + INDI_OFF
    float* __restrict__ dpart,         // ws + DPART_OFF
    float* __restrict__ out)
{
    #pragma clang fp contract(off)
    __shared__ float sd[2][64];
    __shared__ int   si[2][64];
    __shared__ int   sbest[64];
    __shared__ float wdl[4];

    int t    = threadIdx.x;
    int lane = t & 63;
    int wav  = __builtin_amdgcn_readfirstlane(t >> 6); // 0..3, wave-uniform
    int vg   = wav & 1;            // vector group (0/1)
    int kp   = wav >> 1;           // j-half (0/1)
    int vl   = lane & 31;
    int h    = lane >> 5;          // d-half (0/1)
    int vloc = vg * 32 + vl;       // 0..63 in block
    int v    = blockIdx.x * 64 + vloc;

    const float* fx = x + (size_t)v * DIM + h * 32;
    float f[32];
    #pragma unroll
    for (int k = 0; k < 8; ++k) {
        float4 tt = ((const float4*)fx)[k];
        f[4*k+0] = tt.x; f[4*k+1] = tt.y; f[4*k+2] = tt.z; f[4*k+3] = tt.w;
    }

    // ---- A = np.sum(f*f,axis=1), np pairwise (8 accs, stride 8) ----
    // phase 1: both halves compute a 4-block partial in np order (h=0's is
    // the true b=0..3 prefix); h=1 then continues b=4..7 from h=0's prefix.
    float p[8];
    #pragma unroll
    for (int k = 0; k < 8; ++k) p[k] = f[k] * f[k];
    #pragma unroll
    for (int b = 1; b < 4; ++b) {
        #pragma unroll
        for (int k = 0; k < 8; ++k) { float tq = f[8*b+k] * f[8*b+k]; p[k] = p[k] + tq; }
    }
    float r[8];
    #pragma unroll
    for (int k = 0; k < 8; ++k) r[k] = __shfl_xor(p[k], 32);
    #pragma unroll
    for (int b = 0; b < 4; ++b) {
        #pragma unroll
        for (int k = 0; k < 8; ++k) { float tq = f[8*b+k] * f[8*b+k]; r[k] = r[k] + tq; }
    }
    float A = ((r[0] + r[1]) + (r[2] + r[3])) + ((r[4] + r[5]) + (r[6] + r[7]));
    // A valid on h=1 lanes only (h=0 unused)

    // ---- pipelined scan of 128 j-pairs for this kp ----
    int jbase = kp * 256;
    const float2* ebase = EPK + (size_t)(jbase >> 1) * DIM + h * 32;
    const float*  Cs    = Cn + jbase;

    float2 m2 = make_float2(0.0f, 0.0f);
    float bestd = 3.0e38f;
    int   besti = jbase;
    for (int s = 0; s <= 128; ++s) {
        int jp0 = s < 128 ? s : 127;       // h=0: pair s (clamped, dummy at end)
        int jp1 = s > 0 ? s - 1 : 0;       // h=1: pair s-1 (clamped, dummy at start)
        float rx = __shfl_xor(m2.x, 32);   // h=1 receives h=0's half-chain
        float ry = __shfl_xor(m2.y, 32);
        float2 m;
        m.x = h ? rx : 0.0f;
        m.y = h ? ry : 0.0f;
        int jp = h ? jp1 : jp0;
        const float2* ep = ebase + (size_t)jp * DIM;
        #pragma unroll
        for (int dd = 0; dd < 32; ++dd) {
            float2 e2 = ep[dd];
            m.x = __builtin_fmaf(f[dd], e2.x, m.x);   // packable pair
            m.y = __builtin_fmaf(f[dd], e2.y, m.y);
        }
        if (s) {   // s uniform -> scalar branch; h=1 lanes hold full dots
            // t1 = 2m exact => fl(A - t1) == fma(-2,m,A); then + C (np order)
            float c0 = Cs[2*jp1];          // uniform -> s_load
            float c1 = Cs[2*jp1 + 1];
            float d0 = __builtin_fmaf(-2.0f, m.x, A) + c0;
            float d1 = __builtin_fmaf(-2.0f, m.y, A) + c1;
            int j0 = jbase + 2*jp1;
            if (d0 < bestd) { bestd = d0; besti = j0; }
            if (d1 < bestd) { bestd = d1; besti = j0 + 1; }
        }
        m2 = m;
    }

    if (h == 1) { sd[kp][vloc] = bestd; si[kp][vloc] = besti; }
    __syncthreads();

    if (t < 64) {
        float b0 = sd[0][t]; int i0 = si[0][t];
        float b1 = sd[1][t]; int i1 = si[1][t];
        int bi = (b1 < b0) ? i1 : i0;      // strict < : kp0 wins ties (lower j)
        sbest[t] = bi;
        out[IND_OFF + blockIdx.x * 64 + t] = (float)bi;
        indI[blockIdx.x * 64 + t] = bi;
    }
    __syncthreads();

    // epilogue (r4 form, static indexing): wave handles 16-float quarter
    int bi = sbest[lane];
    int v2 = blockIdx.x * 64 + lane;
    const float* qrow = ET + (size_t)bi * DIM + wav * 16;
    const float* xrow = x + (size_t)v2 * DIM + wav * 16;
    float* orow = out + Q_OFF + (size_t)v2 * DIM + wav * 16;
    float dl = 0.0f;
    #pragma unroll
    for (int k = 0; k < 4; ++k) {
        float4 tq = ((const float4*)qrow)[k];
        float4 tx = ((const float4*)xrow)[k];
        float r0 = tq.x - tx.x;
        float r1 = tq.y - tx.y;
        float r2 = tq.z - tx.z;
        float r3 = tq.w - tx.w;
        dl = __builtin_fmaf(r0, r0, dl); dl = __builtin_fmaf(r1, r1, dl);
        dl = __builtin_fmaf(r2, r2, dl); dl = __builtin_fmaf(r3, r3, dl);
        ((float4*)orow)[k] = tq;
    }
    #pragma unroll
    for (int off = 32; off > 0; off >>= 1) dl += __shfl_down(dl, off);
    if (lane == 0) wdl[wav] = dl;
    __syncthreads();
    if (t == 0)
        dpart[blockIdx.x] = ((wdl[0] + wdl[1]) + (wdl[2] + wdl[3]));
}

// ============ stats: 4 blocks x 8 waves per code, int4 ballot scan =======
// Same as r9 but pesum written TRANSPOSED [q][d][j] so vq_emit coalesces.
__global__ __launch_bounds__(512) void vq_stats(
    const float* __restrict__ x,
    const int* __restrict__ indI,      // ws + INDI_OFF
    float* __restrict__ pcnt,          // ws + PCNT_OFF    [4][K]
    float* __restrict__ pesumT)        // ws + PESUMT_OFF  [4][DIM][K]
{
    __shared__ float p[8][DIM];
    __shared__ float c[8];
    int j    = blockIdx.x >> 2;
    int q    = blockIdx.x & 3;
    int lane = threadIdx.x & 63;
    int w    = __builtin_amdgcn_readfirstlane(threadIdx.x >> 6);

    int seg  = q * 8 + w;              // 0..31
    int base = seg * (NVEC / 32);      // 4096 ids per segment

    float acc = 0.0f;
    int   cnt = 0;
    for (int i = 0; i < NVEC / 32; i += 256) {
        int4 idv = ((const int4*)(indI + base + i))[lane];  // 256 ids/wave
        unsigned long long m0 = __ballot(idv.x == j);
        unsigned long long m1 = __ballot(idv.y == j);
        unsigned long long m2 = __ballot(idv.z == j);
        unsigned long long m3 = __ballot(idv.w == j);
        cnt += (int)(__popcll(m0) + __popcll(m1) + __popcll(m2) + __popcll(m3));
        while (m0) { int b = __builtin_ctzll(m0); m0 &= m0 - 1;
                     acc += x[(size_t)(base + i + 4*b + 0) * DIM + lane]; }
        while (m1) { int b = __builtin_ctzll(m1); m1 &= m1 - 1;
                     acc += x[(size_t)(base + i + 4*b + 1) * DIM + lane]; }
        while (m2) { int b = __builtin_ctzll(m2); m2 &= m2 - 1;
                     acc += x[(size_t)(base + i + 4*b + 2) * DIM + lane]; }
        while (m3) { int b = __builtin_ctzll(m3); m3 &= m3 - 1;
                     acc += x[(size_t)(base + i + 4*b + 3) * DIM + lane]; }
    }
    p[w][lane] = acc;
    if (lane == 0) c[w] = (float)cnt;
    __syncthreads();
    if (w == 0) {
        float s = ((p[0][lane] + p[1][lane]) + (p[2][lane] + p[3][lane]))
                + ((p[4][lane] + p[5][lane]) + (p[6][lane] + p[7][lane]));
        pesumT[((size_t)q * DIM + lane) * K + j] = s;   // transposed
        if (lane == 0)
            pcnt[q * K + j] = ((c[0] + c[1]) + (c[2] + c[3]))
                            + ((c[4] + c[5]) + (c[6] + c[7]));
    }
}

// ============ nf: counts -> ncs, n, csz; diff (tiny, 1 block) ============
__global__ __launch_bounds__(512) void vq_nf(
    const float* __restrict__ cluster_size,
    float* __restrict__ ws,
    float* __restrict__ out)
{
    __shared__ float wsum[8];
    __shared__ float dsum_sh[8];
    __shared__ float n_sh;
    int j = threadIdx.x;

    float cj = ((ws[PCNT_OFF + 0*K + j] + ws[PCNT_OFF + 1*K + j])
              + (ws[PCNT_OFF + 2*K + j] + ws[PCNT_OFF + 3*K + j]));
    float ncs = DECAYF * cluster_size[j] + OMDF * cj;
    out[NCS_OFF + j] = ncs;

    float dsum = 0.0f;
    #pragma unroll
    for (int k = 0; k < NBLK_ASSIGN / 512; ++k)
        dsum += ws[DPART_OFF + k * 512 + j];

    float s = ncs;
    #pragma unroll
    for (int off = 32; off > 0; off >>= 1) {
        s    += __shfl_down(s, off);
        dsum += __shfl_down(dsum, off);
    }
    if ((j & 63) == 0) { wsum[j >> 6] = s; dsum_sh[j >> 6] = dsum; }
    __syncthreads();
    if (j == 0) {
        float n = 0.f, dtot = 0.f;
        #pragma unroll
        for (int w = 0; w < 8; ++w) { n += wsum[w]; dtot += dsum_sh[w]; }
        n_sh = n;
        out[DIFF_OFF] = dtot * (1.0f / 8388608.0f);  // 2^23: exact
    }
    __syncthreads();
    float n = n_sh;
    ws[CSZ_OFF + j] = (ncs + EPSF) / (n + (float)K * EPSF) * n;
}

// ============ emit: EMA + normalize, fully coalesced (64 blocks) =========
__global__ __launch_bounds__(512) void vq_emit(
    const float* __restrict__ embed_avg,
    const float* __restrict__ ws,
    float* __restrict__ out)
{
    int d = blockIdx.x;    // 0..63
    int j = threadIdx.x;   // 0..511
    float es = ((ws[PESUMT_OFF + ((size_t)0*DIM + d) * K + j]
               + ws[PESUMT_OFF + ((size_t)1*DIM + d) * K + j])
              + (ws[PESUMT_OFF + ((size_t)2*DIM + d) * K + j]
               + ws[PESUMT_OFF + ((size_t)3*DIM + d) * K + j]));
    float ea = DECAYF * embed_avg[d * K + j] + OMDF * es;
    out[NEA_OFF + d * K + j] = ea;
    out[NE_OFF  + d * K + j] = ea / ws[CSZ_OFF + j];
}

// ============ launch ============
extern "C" void kernel_launch(void* const* d_in, const int* in_sizes, int n_in,
                              void* d_out, int out_size, void* d_ws, size_t ws_size,
                              hipStream_t stream) {
    const float* x            = (const float*)d_in[0];
    const float* embed        = (const float*)d_in[1];
    const float* cluster_size = (const float*)d_in[2];
    const float* embed_avg    = (const float*)d_in[3];
    float* out = (float*)d_out;
    float* ws  = (float*)d_ws;
    int*   indI = (int*)(ws + INDI_OFF);

    vq_prep<<<K / 256, 256, 0, stream>>>(embed, ws);
    vq_assign<<<NBLK_ASSIGN, 256, 0, stream>>>(
        x, ws + ET_OFF, (const float2*)(ws + EPK_OFF), ws + C_OFF,
        indI, ws + DPART_OFF, out);
    vq_stats<<<K * 4, 512, 0, stream>>>(
        x, indI, ws + PCNT_OFF, ws + PESUMT_OFF);
    vq_nf<<<1, 512, 0, stream>>>(cluster_size, ws, out);
    vq_emit<<<DIM, 512, 0, stream>>>(embed_avg, ws, out);
}